// Round 8
// baseline (402.294 us; speedup 1.0000x reference)
//
#include <hip/hip_runtime.h>
#include <stdint.h>

// W8A8B32O32 Linear: Y[m,n] = round(out_scale * sum_k X[m,k]*W[n,k] + bias_scale * bias[n])
// Harness materializes integer inputs as int32 -> pre-pass packs to int8 in d_ws (exact),
// then DMA-staged mfma GEMM.
//
// Round 13: dependency-enforced read/MFMA interleave + wave-group phase stagger.
// Evidence: R12 == R9 to 0.1us (compiler canonicalizes source read order); corrected
// accounting: 192 ds_read_b128/tile = 2304 cyc port + 2612 cyc/SIMD MFMA + ~500 DMA/bar
// == measured 5475 cyc/tile -> FULLY SERIAL. Cause: separate per-slice register arrays
// have no WAR hazard -> compiler bunches reads, barrier-locked waves alternate phases
// in lockstep (port and pipe never co-run).
// Fix (this round):
//  (1) TWO rotating fragment sets across FOUR k-slices (mfma_i32_32x32x32_i8, K=32):
//      RD(0,k0) MM(0) RD(1,k1) MM(1) RD(0,k2) MM(0) RD(1,k3) MM(1).
//      RD(0,k2) has WAR on MM(0,k0); MM(0,k2) RAW on RD(0,k2) -> alternation is
//      dataflow-enforced; compiler must emit counted lgkm waits per 6-read group.
//  (2) wave-group stagger: SIMD mapping is w%4, so groups {0-3},{4-7} place one wave
//      per SIMD each. Group B order: RD RD MM RD MM RD MM MM (one read-stage ahead)
//      -> per SIMD one wave feeds the LDS port while the other feeds the MFMA pipe.
//      Stages balance: 48 reads=576 cyc port vs 16 MFMA/SIMD=586 cyc pipe.
//  (3) mfma_i32_32x32x32_i8: +12% rate vs 16x16x64 (4404 vs 3944 TOPS), half the
//      instructions, acc unchanged at 128 VGPR. A: lane l -> row l&31, k=(l>>5)*16+e.
//      B: col l&31, same k (mirrors the VERIFIED 16x16x64 mapping &15->&31,>>4->>>5).
//      C/D (guide-verified, dtype-indep): col=l&31, row=(reg&3)+8*(reg>>2)+4*(l>>5).
//
//  - 256x256 tile, BK=128, 8 waves (2M x 4N -> 128x64/wave), double-buffered 128 KiB LDS
//  - XOR chunk swizzle (chunk j of row r at LDS slot j^(r&7)) via pre-swizzled global
//    source; read slot = (2ks+hi)^(row&7) -- same verified relation as R6-R12
//  - per K-tile t: STAGE(t+1 -> buf^1) ; sched_barrier ; staggered compute ; __syncthreads
//
// Hazard ledger (1 barrier/tile, unchanged from R9/R12):
//   STAGE t+1 overwrites tile t-1 (reads retired at bottom-of-(t-1) lgkm0+barrier) OK
//   reads buf[t&1] vs DMA into buf^1: disjoint 32KB halves                         OK
//   __syncthreads drains own staging (issued ~3000 cyc earlier, HBM lat ~900) => free
//   fr WAR/RAW chains are per-wave register deps -> hardware/compiler handled.
//
// NOTE: per-replay dur_us includes ~240us fixed harness restore/poison; GEMM is the lever.

typedef int v4i  __attribute__((ext_vector_type(4)));
typedef int v16i __attribute__((ext_vector_type(16)));

#define BM 256
#define BN 256
#define BK 128
#define KK 4096
#define KT (KK / BK)   // 32

// ---------------- pack: 4x int32 -> 4x int8 in one dword (coalesced, ~roofline) ----------------
__global__ __launch_bounds__(256)
void pack_i32_to_i8(const v4i* __restrict__ src, int* __restrict__ dst, int n4) {
    int i = blockIdx.x * blockDim.x + threadIdx.x;   // one thread = 4 elements
    if (i >= n4) return;
    v4i a = src[i];
    dst[i] = (a[0] & 0xff) | ((a[1] & 0xff) << 8) | ((a[2] & 0xff) << 16) | (a[3] << 24);
}

// ---------------- GEMM ----------------
__device__ __forceinline__ void gld_lds16(const void* g, void* lds) {
    __builtin_amdgcn_global_load_lds(
        (const __attribute__((address_space(1))) unsigned int*)g,
        (__attribute__((address_space(3))) unsigned int*)lds,
        16, 0, 0);
}

#define MFMA32 __builtin_amdgcn_mfma_i32_32x32x32_i8

// 6 ds_read_b128 of k-slice ks into set S (A mtiles 0..3, B ntiles 0..1).
// slot = (2*ks + hi) ^ (row&7); mt/nt stride = 32 rows * 128 B = 4096.
#define RD(S, ks) do {                                                            \
    const int sa_ = ((((ks) << 1) | hi) ^ s3a) << 4;                              \
    const int sb_ = ((((ks) << 1) | hi) ^ s3b) << 4;                              \
    fr[S][0] = *(const v4i*)(sAb + rowAb +     0 + sa_);                          \
    fr[S][1] = *(const v4i*)(sAb + rowAb +  4096 + sa_);                          \
    fr[S][2] = *(const v4i*)(sAb + rowAb +  8192 + sa_);                          \
    fr[S][3] = *(const v4i*)(sAb + rowAb + 12288 + sa_);                          \
    fr[S][4] = *(const v4i*)(sBb + rowBb +     0 + sb_);                          \
    fr[S][5] = *(const v4i*)(sBb + rowBb +  4096 + sb_);                          \
} while (0)

// 8 MFMA consuming set S.
#define MM(S) do {                                                                \
    acc[0][0] = MFMA32(fr[S][0], fr[S][4], acc[0][0], 0, 0, 0);                   \
    acc[0][1] = MFMA32(fr[S][0], fr[S][5], acc[0][1], 0, 0, 0);                   \
    acc[1][0] = MFMA32(fr[S][1], fr[S][4], acc[1][0], 0, 0, 0);                   \
    acc[1][1] = MFMA32(fr[S][1], fr[S][5], acc[1][1], 0, 0, 0);                   \
    acc[2][0] = MFMA32(fr[S][2], fr[S][4], acc[2][0], 0, 0, 0);                   \
    acc[2][1] = MFMA32(fr[S][2], fr[S][5], acc[2][1], 0, 0, 0);                   \
    acc[3][0] = MFMA32(fr[S][3], fr[S][4], acc[3][0], 0, 0, 0);                   \
    acc[3][1] = MFMA32(fr[S][3], fr[S][5], acc[3][1], 0, 0, 0);                   \
} while (0)

__global__ __launch_bounds__(512, 2)
void w8a8_gemm_kernel(const int8_t* __restrict__ X,
                      const int8_t* __restrict__ W,
                      const int*    __restrict__ bias,
                      const float*  __restrict__ out_scale_p,
                      const float*  __restrict__ bias_scale_p,
                      int*          __restrict__ Y,
                      int M, int N)
{
    __shared__ __align__(16) int8_t sA[2 * BM * BK];  // 64 KB (double-buffered)
    __shared__ __align__(16) int8_t sB[2 * BN * BK];  // 64 KB

    const int tid = threadIdx.x;         // 0..511

    // ---- block -> tile mapping with 2D XCD chunking (8 XCDs, each owns 8x8 tiles) ----
    const int nbx = N / BN;              // 16 expected
    const int nby = M / BM;              // 32 expected
    int bx, by;
    {
        const int wg = blockIdx.x;
        if (nbx == 16 && nby == 32) {
            const int x = wg & 7;        // XCD (dispatch round-robins blockIdx % 8)
            const int k = wg >> 3;       // 0..63 within XCD
            bx = ((x & 1) << 3) | (k & 7);
            by = ((x >> 1) << 3) | (k >> 3);
        } else { bx = wg % nbx; by = wg / nbx; }
    }
    const int bn = bx * BN;
    const int bm = by * BM;

    const float out_scale  = *out_scale_p;
    const float bias_scale = *bias_scale_p;

    const int8_t* Abase = X + (size_t)bm * KK;
    const int8_t* Bbase = W + (size_t)bn * KK;

    // ---- staging thread map: half-tile = 128 rows x 8 chunks(16B), 2 gld rounds ----
    // LDS[r][j] holds global chunk j^(r&7) of row r (XOR swizzle via SOURCE address
    // permutation; LDS dest linear, DMA-compatible). Verified R6-R12.
    const int r0  = tid >> 3;                       // 0..63 (round 0 rows; round 1 = +64)
    const int j0  = tid & 7;
    const int sw  = (j0 ^ (r0 & 7)) << 4;           // pre-swizzled in-row byte offset
    const size_t gOff = (size_t)r0 * KK + sw;
    const int  lOff = tid << 4;

#define STAGE(gbase, lds, t, h) do {                                              \
        const int8_t* _g = (gbase) + (size_t)((h) * 128) * KK                     \
                                   + (size_t)(t) * BK + gOff;                     \
        int8_t* _l = (lds) + (((t) & 1) << 15) + ((h) << 14) + lOff;              \
        gld_lds16(_g,                  _l);                                       \
        gld_lds16(_g + (size_t)64 * KK, _l + 8192);                               \
    } while (0)

    // ---- fragment read map (32x32x32 i8: lane l -> row/col l&31, k-half hi=l>>5) ----
    const int w    = tid >> 6;
    const int l    = tid & 63;
    const int pg   = w >> 2;                        // phase group: one wave per SIMD each
    const int wmw  = w >> 2;                        // 0..1  (M wave)
    const int wnw  = w & 3;                         // 0..3  (N wave)
    const int ln31 = l & 31;
    const int hi   = l >> 5;
    const int arow = (wmw << 7) + ln31;             // wave A row base + lane row (0..255)
    const int brow = (wnw << 6) + ln31;             // wave B row base + lane row (0..255)
    const int s3a  = arow & 7;                      // mt*32 doesn't change row&7
    const int s3b  = brow & 7;
    const int rowAb = arow << 7;                    // byte base of lane's A row
    const int rowBb = brow << 7;

    v16i acc[4][2];
    const v16i vz16 = {0,0,0,0, 0,0,0,0, 0,0,0,0, 0,0,0,0};
#pragma unroll
    for (int i = 0; i < 4; ++i)
#pragma unroll
        for (int j = 0; j < 2; ++j)
            acc[i][j] = vz16;

    // ---- prologue: stage tile 0 into buf0, land it ----
    STAGE(Abase, sA, 0, 0); STAGE(Abase, sA, 0, 1);
    STAGE(Bbase, sB, 0, 0); STAGE(Bbase, sB, 0, 1);
    __syncthreads();   // vmcnt(0): tile 0 landed

#pragma unroll 2
    for (int t = 0; t < KT; ++t) {
        const int bo = (t & 1) << 15;
        const int8_t* sAb = sA + bo;
        const int8_t* sBb = sB + bo;

        // ---- stage tile t+1 into the other buffer (max slack before the drain) ----
        if (t + 1 < KT) {
            STAGE(Abase, sA, t + 1, 0); STAGE(Abase, sA, t + 1, 1);
            STAGE(Bbase, sB, t + 1, 0); STAGE(Bbase, sB, t + 1, 1);
        }
        __builtin_amdgcn_sched_barrier(0);   // region split: staging stays at top

        // ---- compute tile t: WAR-enforced R/M alternation, group-B staggered ----
        {
            v4i fr[2][6];
            if (pg == 0) {
                RD(0, 0); MM(0);
                RD(1, 1); MM(1);
                RD(0, 2); MM(0);
                RD(1, 3); MM(1);
            } else {
                RD(0, 0);
                RD(1, 1); MM(0);
                RD(0, 2); MM(1);
                RD(1, 3); MM(0);
                MM(1);
            }
        }

        // ---- single barrier: drains own staging loads (issued ~3000 cyc ago => free)
        //      + own ds_reads; publishes buf[t+1], retires buf[t] reads for all waves ----
        __syncthreads();
    }
#undef STAGE

    // ---- epilogue. 32x32 C/D (verified formula): col(n)=l&31,
    //      row(m)=(reg&3) + 8*(reg>>2) + 4*hi.  Stores: per (mt,reg), nt-inner ->
    //      half-wave writes 128B contiguous, nt pairs extend to 256B. ----
    float bbv[2];
#pragma unroll
    for (int j = 0; j < 2; ++j)
        bbv[j] = (float)bias[bn + (wnw << 6) + (j << 5) + ln31] * bias_scale;
#pragma unroll
    for (int mt = 0; mt < 4; ++mt) {
#pragma unroll
        for (int r = 0; r < 16; ++r) {
            const int m = bm + (wmw << 7) + (mt << 5) + (hi << 2) + (r & 3) + ((r >> 2) << 3);
            int* yrow = Y + (size_t)m * N + bn + (wnw << 6) + ln31;
#pragma unroll
            for (int nt = 0; nt < 2; ++nt) {
                const float v = (float)acc[mt][nt][r] * out_scale + bbv[nt];
                yrow[nt << 5] = (int)rintf(v);
            }
        }
    }
}

extern "C" void kernel_launch(void* const* d_in, const int* in_sizes, int n_in,
                              void* d_out, int out_size, void* d_ws, size_t ws_size,
                              hipStream_t stream) {
    const int* x32 = (const int*)d_in[0];   // int8 values stored as int32
    const int* w32 = (const int*)d_in[1];
    const int*    bias = (const int*)d_in[2];
    const float*  os   = (const float*)d_in[3];
    const float*  bs   = (const float*)d_in[4];
    int* out = (int*)d_out;

    const int K = KK;
    const int M = in_sizes[0] / K;   // 8192
    const int N = in_sizes[1] / K;   // 4096
    const int nx = in_sizes[0];      // 33554432
    const int nw = in_sizes[1];      // 16777216

    int8_t* x8 = (int8_t*)d_ws;              // 33.5 MB
    int8_t* w8 = x8 + (size_t)nx;            // 16.8 MB  (total 50.3 MB < ws_size)

    pack_i32_to_i8<<<dim3(nx / 4 / 256), dim3(256), 0, stream>>>((const v4i*)x32, (int*)x8, nx / 4);
    pack_i32_to_i8<<<dim3(nw / 4 / 256), dim3(256), 0, stream>>>((const v4i*)w32, (int*)w8, nw / 4);

    dim3 grid((N / BN) * (M / BM));  // (16 x 32) tiles -> 512 blocks = 2 rounds of 256 CUs
    dim3 block(512);
    hipLaunchKernelGGL(w8a8_gemm_kernel, grid, block, 0, stream,
                       x8, w8, bias, os, bs, out, M, N);
}